// Round 18
// baseline (32.700 us; speedup 1.0000x reference)
//
#include <hip/hip_runtime.h>

// QuanvolutionSelfAttentionClassifier on MI355X — round 18: touch-optimal A
// via 32x32x16 MFMA.
//
// Algebra (verified R1-R17): softmax over length-1 axis == 1 ->
// attn_weights == mean_embeds (rotation/entangle dead). l = c*196+p ->
// d = p&3; pixel (r,cc): d = (2*((r>>1)&1) + (cc>>1)) & 3.
//   logits[j] = lin_b[j] + sum_d M[d]*(cst[d][j] + T[d][j])
//   M[d] = a + sum_pix x*gm,  T[d][j] = sum_{pix in d} x*G[pix][j]
//
// F~25us fixed-term identity (survived R14-R17 work cuts): A-load TA touch
// rate. 16x16x32's A fragment (row=lane&15, 4 k-groups of 8) makes each 16B
// load instruction touch 16 rows x 2 lines = 32 touches/KB — 2x the optimal
// 16/KB of a coalesced stream -> x-delivery capped ~3 TB/s, insensitive to
// L3 (matches "warm==cold, pipes idle" since R11; same model that predicted
// R13's win). Fix: mfma_f32_32x32x16_bf16 — A row=lane&31, 8 CONSECUTIVE k
// per lane -> per 16B instr: 32 rows x 1 line = touch-optimal, no staging.
// Bonus: 784 = 49*16 exactly -> no K-tail. C layout (m74/m101-verified):
// col=lane&31, row=(reg&3)+8*(reg>>2)+4*(lane>>5). A/B symmetric-k fill
// (same trick verified on 16x16x32; flagged risk).
// 256 blocks x 1024 thr: 16 waves = 4 strips (32 samples) x 4 K-quarters;
// B bf16 [64 cols(48 real)][784 k] = 98 KB LDS; 2 MFMA + 2 ds_read_b128
// per 16-k step; K-reduce + C-exchange in dead-B LDS.

typedef __attribute__((ext_vector_type(8))) short bf16x8;
typedef __attribute__((ext_vector_type(16))) float f32x16;
typedef __attribute__((ext_vector_type(4))) unsigned int uint4v;

union BU { uint4v u; bf16x8 b; };
union AB { unsigned int u[4]; bf16x8 b; };

__device__ __forceinline__ unsigned rne16(float f) {
  const unsigned u = __float_as_uint(f);
  return (u + 0x7FFFu + ((u >> 16) & 1u)) >> 16;
}

#define CST_F 25088   // float idx in ws (after 50176 shorts): cst[40]
#define A_F   25128   // float idx: a

// prep: B-image bf16, BYTE-IDENTICAL to main's LDS layout.
// i -> e=i&7, ln=(i>>3)&63, c=i>>9 (c = s*2+nt, 0..97);
// col = nt*32 + (ln&31); k = s*16 + (ln>>5)*8 + e  (always < 784).
// Chunk c: shorts [c*512 + ln*8 + e]. cols 48-63 zero.
__global__ void qsac_prep(const float* __restrict__ cw, const float* __restrict__ cb,
                          const float* __restrict__ lw, float* __restrict__ wsf) {
  unsigned short* gt = (unsigned short*)wsf;
  const int i = blockIdx.x * 256 + threadIdx.x;  // 196 x 256 = 50176
  const int e = i & 7, ln = (i >> 3) & 63, c = i >> 9;
  const int s = c >> 1, nt = c & 1;
  const int col = nt * 32 + (ln & 31);
  const int k = s * 16 + (ln >> 5) * 8 + e;
  float val = 0.f;
  if (col < 48) {
    const int r = k / 28, cc = k - r * 28;
    const int kh = r & 1, kw = cc & 1;
    const int p = (r >> 1) * 14 + (cc >> 1);
    const int dpix = (2 * ((r >> 1) & 1) + (cc >> 1)) & 3;
    const int cd = col / 12, cj = col - cd * 12;
    if (cd == dpix) {
      const float w0 = cw[(kh << 1) + kw],     w1 = cw[4 + (kh << 1) + kw],
                  w2 = cw[8 + (kh << 1) + kw], w3 = cw[12 + (kh << 1) + kw];
      if (cj < 10)
        val = w0 * lw[cj * 784 + p]       + w1 * lw[cj * 784 + 196 + p] +
              w2 * lw[cj * 784 + 392 + p] + w3 * lw[cj * 784 + 588 + p];
      else if (cj == 10)
        val = (w0 + w1 + w2 + w3) * (1.0f / 196.0f);
    }
  }
  gt[c * 512 + ln * 8 + e] = (unsigned short)rne16(val);

  if (blockIdx.x == 0) {
    const int u = threadIdx.x;
    if (u < 40) {
      const int d = u / 10, j = u - (u / 10) * 10;
      const float b0 = cb[0], b1 = cb[1], b2 = cb[2], b3 = cb[3];
      float s2 = 0.f;
#pragma unroll 7
      for (int q = d; q < 196; q += 4)
        s2 += b0 * lw[j * 784 + q]       + b1 * lw[j * 784 + 196 + q] +
              b2 * lw[j * 784 + 392 + q] + b3 * lw[j * 784 + 588 + q];
      wsf[CST_F + u] = s2;
    } else if (u == 40) {
      wsf[A_F] = (cb[0] + cb[1] + cb[2] + cb[3]) * 0.25f;
    }
  }
}

__global__ __launch_bounds__(1024)
__attribute__((amdgpu_waves_per_eu(4, 4))) void qsac_main(
    const float* __restrict__ x, const float* __restrict__ wsf,
    const float* __restrict__ lin_b, float* __restrict__ out) {
  // B in LDS: chunk c (=s*2+nt, 0..97): 16B/lane at byte c*1024 + lane*16.
  __shared__ unsigned int smemu[25088];  // 100,352 B -> 1 block/CU

  const int tid = threadIdx.x;
  const int lane = tid & 63;
  const int wid = __builtin_amdgcn_readfirstlane(tid >> 6);  // 0..15
  const int strip = wid & 3;    // 4 strips x 32 samples = 128 samples/block
  const int kq = wid >> 2;      // K-quarter: steps [q0,q1)
  const int nn = lane & 31;     // A-row (sample-in-strip) AND B-col-in-tile
  const int g = lane >> 5;      // k-group: 8 consecutive k at g*8
  const int sbase = blockIdx.x * 128 + strip * 32;
  const float* xrow = x + (size_t)(sbase + nn) * 784;

  // ---- B staging: pure 16B global_load_lds copy; 98 chunks over 16 waves.
  {
    const char* wsb = (const char*)wsf;
#pragma unroll
    for (int i = 0; i < 7; ++i) {
      const int c = i * 16 + wid;
      if (c < 98) {
        __builtin_amdgcn_global_load_lds(
            (const __attribute__((address_space(1))) unsigned int*)
                (wsb + (size_t)(c * 64 + lane) * 16),
            (__attribute__((address_space(3))) unsigned int*)&smemu[c * 256],
            16, 0, 0);
      }
    }
  }
  __syncthreads();  // drains vmcnt -> B image complete

  f32x16 acc0, acc1;
#pragma unroll
  for (int r = 0; r < 16; ++r) { acc0[r] = 0.f; acc1[r] = 0.f; }

  auto tile = [&](const float4& a, const float4& b2, int s) {
    BU bh0, bh1;
    const unsigned int* bb = smemu + s * 512 + lane * 4;
    bh0.u = *(const uint4v*)bb;
    bh1.u = *(const uint4v*)(bb + 256);
    AB Ah;
    Ah.u[0] = rne16(a.x)  | (rne16(a.y)  << 16);
    Ah.u[1] = rne16(a.z)  | (rne16(a.w)  << 16);
    Ah.u[2] = rne16(b2.x) | (rne16(b2.y) << 16);
    Ah.u[3] = rne16(b2.z) | (rne16(b2.w) << 16);
    acc0 = __builtin_amdgcn_mfma_f32_32x32x16_bf16(Ah.b, bh0.b, acc0, 0, 0, 0);
    acc1 = __builtin_amdgcn_mfma_f32_32x32x16_bf16(Ah.b, bh1.b, acc1, 0, 0, 0);
  };

  auto ldA = [&](int s, float4& a, float4& b2) {
    const float* p = xrow + s * 16 + g * 8;  // 8 consecutive floats, no tail
    a = *(const float4*)p;
    b2 = *(const float4*)(p + 4);
  };

  // K-quarter [s0, s1): kq0 gets 13 steps, others 12. Depth-1 ping-pong.
  const int s0 = (kq == 0) ? 0 : 13 + (kq - 1) * 12;
  const int s1 = s0 + ((kq == 0) ? 13 : 12);
  float4 xa, xb, na, nb;
  ldA(s0, xa, xb);
#pragma unroll 1
  for (int s = s0; s < s1 - 1; ++s) {
    ldA(s + 1, na, nb);
    tile(xa, xb, s);
    xa = na; xb = nb;
  }
  tile(xa, xb, s1 - 1);

  // ---- 4-way K-reduction in dead-B LDS ----
  __syncthreads();  // b1: all waves past the loop -> B dead
  float* red = (float*)smemu;  // [4 strips][3 kq-1][64 lanes][32] = 98,304 B
  if (kq > 0) {
    float* rp = red + ((strip * 3 + (kq - 1)) * 64 + lane) * 32;
#pragma unroll
    for (int r = 0; r < 16; ++r) { rp[r] = acc0[r]; rp[16 + r] = acc1[r]; }
  }
  __syncthreads();  // b2
  if (kq == 0) {
#pragma unroll
    for (int q = 0; q < 3; ++q) {
      const float* rp = red + ((strip * 3 + q) * 64 + lane) * 32;
#pragma unroll
      for (int r = 0; r < 16; ++r) { acc0[r] += rp[r]; acc1[r] += rp[16 + r]; }
    }
  }
  __syncthreads();  // b3: reduction reads done -> area reusable for cx

  if (kq == 0) {
    // C-exchange: cx[strip][32 rows][68]; row=(r&3)+8*(r>>2)+4*g, col=lane&31.
    float* cx = (float*)smemu + strip * (32 * 68);
#pragma unroll
    for (int r = 0; r < 16; ++r) {
      const int row = (r & 3) + 8 * (r >> 2) + 4 * g;
      cx[row * 68 + nn] = acc0[r];
      cx[row * 68 + 32 + nn] = acc1[r];
    }
    __builtin_amdgcn_wave_barrier();  // same-wave LDS pipe is in-order

    if (lane < 32) {
      float Y[48];
#pragma unroll
      for (int q = 0; q < 12; ++q) {
        const float4 t4 = *(const float4*)&cx[lane * 68 + q * 4];
        Y[q * 4 + 0] = t4.x; Y[q * 4 + 1] = t4.y;
        Y[q * 4 + 2] = t4.z; Y[q * 4 + 3] = t4.w;
      }
      const float a = wsf[A_F];
      float M[4];
#pragma unroll
      for (int d = 0; d < 4; ++d) M[d] = a + Y[d * 12 + 10];
      float logits[10];
#pragma unroll
      for (int j = 0; j < 10; ++j) {
        float vv = lin_b[j];
#pragma unroll
        for (int d = 0; d < 4; ++d)
          vv += M[d] * (wsf[CST_F + d * 10 + j] + Y[d * 12 + j]);
        logits[j] = vv;
      }
      float mx = logits[0];
#pragma unroll
      for (int j = 1; j < 10; ++j) mx = fmaxf(mx, logits[j]);
      float se = 0.f;
#pragma unroll
      for (int j = 0; j < 10; ++j) se += __expf(logits[j] - mx);
      const float lse = mx + __logf(se);
      float* op = out + (size_t)(sbase + lane) * 10;
#pragma unroll
      for (int j = 0; j < 10; ++j) op[j] = logits[j] - lse;
    }
  }
}

extern "C" void kernel_launch(void* const* d_in, const int* in_sizes, int n_in,
                              void* d_out, int out_size, void* d_ws, size_t ws_size,
                              hipStream_t stream) {
  (void)n_in; (void)ws_size; (void)out_size;
  const float* x = (const float*)d_in[0];
  const float* conv_w = (const float*)d_in[1];
  const float* conv_b = (const float*)d_in[2];
  // d_in[3]/d_in[4] (rotation/entangle) are dead: softmax over length-1 == 1.
  const float* lin_w = (const float*)d_in[5];
  const float* lin_b = (const float*)d_in[6];
  float* out = (float*)d_out;
  float* wsf = (float*)d_ws;

  hipLaunchKernelGGL(qsac_prep, dim3(196), dim3(256), 0, stream,
                     conv_w, conv_b, lin_w, wsf);

  const int B = in_sizes[0] / 784;  // 32768
  const int nblk = B / 128;         // 256 blocks x 1024 threads (1 block/CU)
  hipLaunchKernelGGL(qsac_main, dim3(nblk), dim3(1024), 0, stream,
                     x, wsf, lin_b, out);
}

// Round 19
// 28.136 us; speedup vs baseline: 1.1622x; 1.1622x over previous
//
#include <hip/hip_runtime.h>

// QuanvolutionSelfAttentionClassifier on MI355X — round 19: zero-redundancy
// A-transactions (k-remap), on the R17 best structure.
//
// Algebra (verified R1-R18): softmax over length-1 axis == 1 ->
// attn_weights == mean_embeds (rotation/entangle dead). l = c*196+p ->
// d = p&3; pixel (r,cc): d = (2*((r>>1)&1) + (cc>>1)) & 3.
//   logits[j] = lin_b[j] + sum_d M[d]*(cst[d][j] + T[d][j])
//   M[d] = a + sum_pix x*gm,  T[d][j] = sum_{pix in d} x*G[pix][j]
// Y = X·G via mfma_f32_16x16x32_bf16 (single RNE bf16, error ~3e-3 <<
// margin, verified R17); col = d*12+j; C layout col=lane&15,
// row=(lane>>4)*4+reg — verified 7x (absmax 0.0156 = harness floor).
//
// Transaction recount: R17/R18 both issue 32 fresh + 32 REDUNDANT L1-hit
// A-transactions per k-step (xa,xb separate instructions on the same lines)
// — R18 varied the wrong term. v19 uses the symmetric-k-fill freedom (A and
// B need only the SAME (lane,elem)->k map) to remap
//   (kb,e) -> k = t*32 + kb*4 + (e>=4 ? 16 : 0) + (e&3)
// so instr1 covers one 64B line/row (kb lanes contiguous) and instr2 the
// next: 32 transactions/step, zero redundancy — A-side analog of R13's B
// fix. Row bases 64B-aligned (3136=49*64). Only prep's k formula and ldA's
// offsets change vs R17. Secondary: prep's serial 49-iter cst tail
// parallelized (200 thr x ~10 iters + LDS reduce).

typedef __attribute__((ext_vector_type(8))) short bf16x8;
typedef __attribute__((ext_vector_type(4))) float f32x4;
typedef __attribute__((ext_vector_type(4))) unsigned int uint4v;

union BU { uint4v u; bf16x8 b; };
union AB { unsigned int u[4]; bf16x8 b; };

__device__ __forceinline__ unsigned rne16(float f) {
  const unsigned u = __float_as_uint(f);
  return (u + 0x7FFFu + ((u >> 16) & 1u)) >> 16;
}

#define CST_F 19200   // float idx in ws (after 38400 shorts): cst[40]
#define A_F   19240   // float idx: a

// prep: B-image bf16, BYTE-IDENTICAL to main's LDS layout.
// i -> e=i&7, ln=(i>>3)&63, c=i>>9 (c = t*3+nt, 0..74);
// col=(c%3)*16+(ln&15); k = t*32 + (ln>>4)*4 + (e>=4?16:0) + (e&3).
// Chunk c: shorts [c*512 + ln*8 + e].
__global__ void qsac_prep(const float* __restrict__ cw, const float* __restrict__ cb,
                          const float* __restrict__ lw, float* __restrict__ wsf) {
  __shared__ float cpart[200];
  unsigned short* gt = (unsigned short*)wsf;
  const int i = blockIdx.x * 256 + threadIdx.x;  // 150 x 256 = 38400
  const int e = i & 7, ln = (i >> 3) & 63, c = i >> 9;
  const int t = c / 3, nt = c - t * 3;
  const int col = nt * 16 + (ln & 15);
  const int k = t * 32 + ((ln >> 4) << 2) + ((e >> 2) << 4) + (e & 3);
  float val = 0.f;
  if (k < 784) {
    const int r = k / 28, cc = k - r * 28;
    const int kh = r & 1, kw = cc & 1;
    const int p = (r >> 1) * 14 + (cc >> 1);
    const int dpix = (2 * ((r >> 1) & 1) + (cc >> 1)) & 3;
    const int cd = col / 12, cj = col - cd * 12;
    if (cd == dpix) {
      const float w0 = cw[(kh << 1) + kw],     w1 = cw[4 + (kh << 1) + kw],
                  w2 = cw[8 + (kh << 1) + kw], w3 = cw[12 + (kh << 1) + kw];
      if (cj < 10)
        val = w0 * lw[cj * 784 + p]       + w1 * lw[cj * 784 + 196 + p] +
              w2 * lw[cj * 784 + 392 + p] + w3 * lw[cj * 784 + 588 + p];
      else if (cj == 10)
        val = (w0 + w1 + w2 + w3) * (1.0f / 196.0f);
    }
  }
  gt[c * 512 + ln * 8 + e] = (unsigned short)rne16(val);

  if (blockIdx.x == 0) {
    const int u = threadIdx.x;
    // cst[d][j] = sum_{q==d mod 4} sum_c cb[c]*lw[j*784 + c*196 + q],
    // parallelized: 200 threads = 40 (d,j) groups x 5 chunks of ~10 terms.
    if (u < 200) {
      const int g = u / 5, ch = u - (u / 5) * 5;
      const int d = g / 10, j = g - (g / 10) * 10;
      const float b0 = cb[0], b1 = cb[1], b2 = cb[2], b3 = cb[3];
      float s = 0.f;
#pragma unroll
      for (int n = 0; n < 10; ++n) {
        const int pi = ch + 5 * n;  // p-index / 4
        if (pi < 49) {
          const int q = d + 4 * pi;
          s += b0 * lw[j * 784 + q]       + b1 * lw[j * 784 + 196 + q] +
               b2 * lw[j * 784 + 392 + q] + b3 * lw[j * 784 + 588 + q];
        }
      }
      cpart[u] = s;
    }
    __syncthreads();
    if (u < 40) {
      float s = 0.f;
#pragma unroll
      for (int ch = 0; ch < 5; ++ch) s += cpart[u * 5 + ch];
      wsf[CST_F + u] = s;
    } else if (u == 40) {
      wsf[A_F] = (cb[0] + cb[1] + cb[2] + cb[3]) * 0.25f;
    }
  }
}

__global__ __launch_bounds__(512)
__attribute__((amdgpu_waves_per_eu(4, 4))) void qsac_main(
    const float* __restrict__ x, const float* __restrict__ wsf,
    const float* __restrict__ lin_b, float* __restrict__ out) {
  // B in LDS: chunk c (=t*3+nt): 16B/lane at byte c*1024 + lane*16.
  __shared__ unsigned int smemu[19200];  // 76,800 B -> 2 blocks/CU

  const int tid = threadIdx.x;
  const int lane = tid & 63;
  const int wid = __builtin_amdgcn_readfirstlane(tid >> 6);  // 0..7
  const int strip = wid & 3;    // 4 strips x 16 samples = 64 samples/block
  const int khalf = wid >> 2;   // 0: tiles [0,12); 1: tiles [12,25)
  const int nn = lane & 15, kb = lane >> 4;
  const int sbase = blockIdx.x * 64 + strip * 16;
  const float* xrow = x + (size_t)(sbase + nn) * 784;

  // ---- B staging: pure 16B global_load_lds copy of the ws image.
  {
    const char* wsb = (const char*)wsf;
#pragma unroll
    for (int i = 0; i < 10; ++i) {
      const int c = i * 8 + wid;
      if (c < 75) {
        __builtin_amdgcn_global_load_lds(
            (const __attribute__((address_space(1))) unsigned int*)
                (wsb + (size_t)(c * 64 + lane) * 16),
            (__attribute__((address_space(3))) unsigned int*)&smemu[c * 256],
            16, 0, 0);
      }
    }
  }
  __syncthreads();  // drains vmcnt -> B image complete

  f32x4 acc[3];
#pragma unroll
  for (int nt = 0; nt < 3; ++nt) acc[nt] = (f32x4){0.f, 0.f, 0.f, 0.f};

  auto tile = [&](const float4& a, const float4& b2, int t) {
    BU bh[3];
    const unsigned int* bb = smemu + t * 768 + lane * 4;
#pragma unroll
    for (int nt = 0; nt < 3; ++nt) bh[nt].u = *(const uint4v*)(bb + nt * 256);
    AB Ah;
    Ah.u[0] = rne16(a.x)  | (rne16(a.y)  << 16);
    Ah.u[1] = rne16(a.z)  | (rne16(a.w)  << 16);
    Ah.u[2] = rne16(b2.x) | (rne16(b2.y) << 16);
    Ah.u[3] = rne16(b2.z) | (rne16(b2.w) << 16);
#pragma unroll
    for (int nt = 0; nt < 3; ++nt)
      acc[nt] = __builtin_amdgcn_mfma_f32_16x16x32_bf16(Ah.b, bh[nt].b, acc[nt], 0, 0, 0);
  };

  // A-load, zero-redundancy lines: elems 0-3 at k=t*32+kb*4 (instr 1 covers
  // one 64B line across the 4 kb-lanes of each row), elems 4-7 at +16 floats
  // (the next line). Tail t=24: elems 4-7 have k>=784 -> B rows are zero ->
  // clamp the address to the row start (values don't matter).
  auto ldA = [&](int t, float4& a, float4& b2) {
    const float* p = xrow + t * 32 + kb * 4;
    a = *(const float4*)p;
    const float* p2 = (t < 24) ? (p + 16) : xrow;
    b2 = *(const float4*)p2;
  };

  // K-half [t0, t1): depth-1 ping-pong prefetch (R14: deeper is neutral).
  const int t0 = khalf ? 12 : 0;
  const int t1 = khalf ? 25 : 12;
  float4 xa, xb, na, nb;
  ldA(t0, xa, xb);
#pragma unroll 1
  for (int t = t0; t < t1 - 1; ++t) {
    ldA(t + 1, na, nb);
    tile(xa, xb, t);
    xa = na; xb = nb;
  }
  tile(xa, xb, t1 - 1);

  // ---- pair-reduction + epilogue in dead-B LDS (R17-verified) ----
  __syncthreads();  // all waves past the loop -> B truly dead
  float* red = (float*)smemu;                   // [4 strips][64 lanes][12]
  if (khalf == 1) {
#pragma unroll
    for (int nt = 0; nt < 3; ++nt)
#pragma unroll
      for (int rg = 0; rg < 4; ++rg)
        red[(strip * 64 + lane) * 12 + nt * 4 + rg] = acc[nt][rg];
  }
  __syncthreads();
  if (khalf == 0) {
#pragma unroll
    for (int nt = 0; nt < 3; ++nt)
#pragma unroll
      for (int rg = 0; rg < 4; ++rg)
        acc[nt][rg] += red[(strip * 64 + lane) * 12 + nt * 4 + rg];

    // C exchange (after the reduction area) + per-sample finish.
    float* cx = (float*)smemu + 3072 + strip * (16 * 52);
#pragma unroll
    for (int nt = 0; nt < 3; ++nt)
#pragma unroll
      for (int rg = 0; rg < 4; ++rg)
        cx[(kb * 4 + rg) * 52 + nt * 16 + nn] = acc[nt][rg];
    __builtin_amdgcn_wave_barrier();  // same-wave LDS pipe is in-order

    if (lane < 16) {
      float Y[48];
#pragma unroll
      for (int q = 0; q < 12; ++q) {
        const float4 t4 = *(const float4*)&cx[lane * 52 + q * 4];
        Y[q * 4 + 0] = t4.x; Y[q * 4 + 1] = t4.y;
        Y[q * 4 + 2] = t4.z; Y[q * 4 + 3] = t4.w;
      }
      const float a = wsf[A_F];
      float M[4];
#pragma unroll
      for (int d = 0; d < 4; ++d) M[d] = a + Y[d * 12 + 10];
      float logits[10];
#pragma unroll
      for (int j = 0; j < 10; ++j) {
        float vv = lin_b[j];
#pragma unroll
        for (int d = 0; d < 4; ++d)
          vv += M[d] * (wsf[CST_F + d * 10 + j] + Y[d * 12 + j]);
        logits[j] = vv;
      }
      float mx = logits[0];
#pragma unroll
      for (int j = 1; j < 10; ++j) mx = fmaxf(mx, logits[j]);
      float se = 0.f;
#pragma unroll
      for (int j = 0; j < 10; ++j) se += __expf(logits[j] - mx);
      const float lse = mx + __logf(se);
      float* op = out + (size_t)(sbase + lane) * 10;
#pragma unroll
      for (int j = 0; j < 10; ++j) op[j] = logits[j] - lse;
    }
  }
}

extern "C" void kernel_launch(void* const* d_in, const int* in_sizes, int n_in,
                              void* d_out, int out_size, void* d_ws, size_t ws_size,
                              hipStream_t stream) {
  (void)n_in; (void)ws_size; (void)out_size;
  const float* x = (const float*)d_in[0];
  const float* conv_w = (const float*)d_in[1];
  const float* conv_b = (const float*)d_in[2];
  // d_in[3]/d_in[4] (rotation/entangle) are dead: softmax over length-1 == 1.
  const float* lin_w = (const float*)d_in[5];
  const float* lin_b = (const float*)d_in[6];
  float* out = (float*)d_out;
  float* wsf = (float*)d_ws;

  hipLaunchKernelGGL(qsac_prep, dim3(150), dim3(256), 0, stream,
                     conv_w, conv_b, lin_w, wsf);

  const int B = in_sizes[0] / 784;  // 32768
  const int nblk = B / 64;          // 512 blocks x 512 threads (2 blocks/CU)
  hipLaunchKernelGGL(qsac_main, dim3(nblk), dim3(512), 0, stream,
                     x, wsf, lin_b, out);
}